// Round 1
// baseline (696.947 us; speedup 1.0000x reference)
//
#include <hip/hip_runtime.h>
#include <math.h>

// Problem constants
#define B_ 4
#define L_ 8192
#define D_ 1024
#define M_ (B_ * L_)   // 32768 rows
#define K_ D_          // 1024 reduction dim

// GEMM tiling: 128x128 out tile, BOTH gate+cand per block, BK=32, 4 waves
#define BM 128
#define BN 128
#define BK 32

// Scan chunking: one GEMM block row-tile == one chunk
#define NCH 64          // chunks per batch (L_/CHL)
#define CHL 128         // chunk length == BM

typedef short bf16x8 __attribute__((ext_vector_type(8)));
typedef float f32x4 __attribute__((ext_vector_type(4)));

__device__ __forceinline__ unsigned short f2bf(float f) {
    unsigned u = __float_as_uint(f);
    u += 0x7fff + ((u >> 16) & 1);   // RNE
    return (unsigned short)(u >> 16);
}
__device__ __forceinline__ float bf2f(unsigned short h) {
    return __uint_as_float(((unsigned)h) << 16);
}

__device__ __forceinline__ void async16(const void* g, void* l) {
    __builtin_amdgcn_global_load_lds(
        (const __attribute__((address_space(1))) unsigned int*)g,
        (__attribute__((address_space(3))) unsigned int*)l, 16, 0, 0);
}

// ---------------------------------------------------------------------------
// Weight prep: split Wg, Wc (fp32 [D,D]) into bf16 hi/lo planes.
// ---------------------------------------------------------------------------
__global__ __launch_bounds__(256) void wprep_kernel(
    const float* __restrict__ Wg, const float* __restrict__ Wc,
    unsigned short* __restrict__ Wghi, unsigned short* __restrict__ Wglo,
    unsigned short* __restrict__ Wchi, unsigned short* __restrict__ Wclo)
{
    int idx = (blockIdx.x * 256 + threadIdx.x) * 4;  // over 2*D*D elements
    const int n = D_ * D_;
    const float* src; unsigned short *dh, *dl; int o;
    if (idx < n) { src = Wg; dh = Wghi; dl = Wglo; o = idx; }
    else         { src = Wc; dh = Wchi; dl = Wclo; o = idx - n; }
    float4 v = *(const float4*)(src + o);
    ushort4 hi, lo;
    hi.x = f2bf(v.x); lo.x = f2bf(v.x - bf2f(hi.x));
    hi.y = f2bf(v.y); lo.y = f2bf(v.y - bf2f(hi.y));
    hi.z = f2bf(v.z); lo.z = f2bf(v.z - bf2f(hi.z));
    hi.w = f2bf(v.w); lo.w = f2bf(v.w - bf2f(hi.w));
    *(ushort4*)(dh + o) = hi;
    *(ushort4*)(dl + o) = lo;
}

// ---------------------------------------------------------------------------
// Fused dual GEMM (gate + cand in ONE block) + activation + in-register local
// scan over the 128-timestep chunk. Writes P (prefix gate product within
// chunk) and hloc (local scan, h_in=0) instead of g and c, plus chunk carries.
//
// grid = (M/128, D/128). Per block: 128 timesteps x 128 channels, both mats.
// 4 waves, each 64x64 per matrix = 4x4 frags of 16x16; 96 MFMA per BK=32 step.
// ---------------------------------------------------------------------------
__global__ __launch_bounds__(256, 2) void gemm_scan_kernel(
    const float* __restrict__ X,
    const unsigned short* __restrict__ Wghi, const unsigned short* __restrict__ Wglo,
    const unsigned short* __restrict__ Wchi, const unsigned short* __restrict__ Wclo,
    const float* __restrict__ bg, const float* __restrict__ bc,
    float* __restrict__ P_ws, float* __restrict__ h_ws,
    float* __restrict__ carryA, float* __restrict__ carryB)
{
    __shared__ __align__(16) unsigned short sAhi[BM * BK];   // 8 KB each
    __shared__ __align__(16) unsigned short sAlo[BM * BK];
    __shared__ __align__(16) unsigned short sBghi[BN * BK];
    __shared__ __align__(16) unsigned short sBglo[BN * BK];
    __shared__ __align__(16) unsigned short sBchi[BN * BK];
    __shared__ __align__(16) unsigned short sBclo[BN * BK];
    __shared__ float cw[2][4][16][2];   // cross-wave scan carry, 1 KB

    const int t = threadIdx.x;
    const int lane = t & 63;
    const int w = t >> 6;          // wave 0..3
    const int wrow = w >> 1;       // 0..1  (m half)
    const int wcol = w & 1;        // 0..1  (n half)
    const int quad = lane >> 4;    // 0..3
    const int l16  = lane & 15;

    const int m0 = blockIdx.x * BM;
    const int n0 = blockIdx.y * BN;

    f32x4 accg[4][4] = {};
    f32x4 accc[4][4] = {};

#pragma unroll 1
    for (int k0 = 0; k0 < K_; k0 += BK) {
        __syncthreads();   // all waves done reading previous tiles

        // ---- B staging: async DMA from pre-split bf16 planes (4 planes) ----
        // Each plane 8 KB = 2 passes of 256 threads x 16 B. LDS [128][32] bf16.
#pragma unroll
        for (int p = 0; p < 2; ++p) {
            int o   = t * 16 + p * 4096;       // byte offset in tile
            int row = o >> 6;                  // 64 B per row
            int kc  = (o & 63) >> 1;           // k element offset
            size_t goff = (size_t)(n0 + row) * K_ + k0 + kc;
            async16(Wghi + goff, (char*)sBghi + o);
            async16(Wglo + goff, (char*)sBglo + o);
            async16(Wchi + goff, (char*)sBchi + o);
            async16(Wclo + goff, (char*)sBclo + o);
        }

        // ---- A staging: fp32 load -> split -> ds_write ----
#pragma unroll
        for (int p = 0; p < 4; ++p) {
            int idx = (p * 256 + t) * 4;
            int row = idx >> 5;                // 32 k per row
            int k   = idx & 31;
            float4 v = *(const float4*)(X + (size_t)(m0 + row) * K_ + k0 + k);
            ushort4 hi, lo;
            hi.x = f2bf(v.x); lo.x = f2bf(v.x - bf2f(hi.x));
            hi.y = f2bf(v.y); lo.y = f2bf(v.y - bf2f(hi.y));
            hi.z = f2bf(v.z); lo.z = f2bf(v.z - bf2f(hi.z));
            hi.w = f2bf(v.w); lo.w = f2bf(v.w - bf2f(hi.w));
            *(ushort4*)(sAhi + row * BK + k) = hi;
            *(ushort4*)(sAlo + row * BK + k) = lo;
        }

        __syncthreads();   // drains vmcnt (DMA) + lgkmcnt (ds_write)

        // ---- fragment loads + MFMA (96 per wave per step) ----
        bf16x8 ahi[4], alo[4];
#pragma unroll
        for (int i = 0; i < 4; ++i) {
            int off = (wrow * 64 + i * 16 + l16) * BK + quad * 8;
            ahi[i] = *(const bf16x8*)(sAhi + off);
            alo[i] = *(const bf16x8*)(sAlo + off);
        }
#pragma unroll
        for (int j = 0; j < 4; ++j) {
            int off = (wcol * 64 + j * 16 + l16) * BK + quad * 8;
            bf16x8 bgh = *(const bf16x8*)(sBghi + off);
            bf16x8 bgl = *(const bf16x8*)(sBglo + off);
            bf16x8 bch = *(const bf16x8*)(sBchi + off);
            bf16x8 bcl = *(const bf16x8*)(sBclo + off);
#pragma unroll
            for (int i = 0; i < 4; ++i) {
                accg[i][j] = __builtin_amdgcn_mfma_f32_16x16x32_bf16(ahi[i], bgh, accg[i][j], 0, 0, 0);
                accg[i][j] = __builtin_amdgcn_mfma_f32_16x16x32_bf16(ahi[i], bgl, accg[i][j], 0, 0, 0);
                accg[i][j] = __builtin_amdgcn_mfma_f32_16x16x32_bf16(alo[i], bgh, accg[i][j], 0, 0, 0);
                accc[i][j] = __builtin_amdgcn_mfma_f32_16x16x32_bf16(ahi[i], bch, accc[i][j], 0, 0, 0);
                accc[i][j] = __builtin_amdgcn_mfma_f32_16x16x32_bf16(ahi[i], bcl, accc[i][j], 0, 0, 0);
                accc[i][j] = __builtin_amdgcn_mfma_f32_16x16x32_bf16(alo[i], bch, accc[i][j], 0, 0, 0);
            }
        }
    }

    // =======================================================================
    // Epilogue: bias + activation + in-register affine prefix scan over the
    // 128 timesteps of this chunk. Affine map per step: h -> g*h + c.
    // Composition (later∘earlier): (A2,B2)∘(A1,B1) = (A2*A1, A2*B1+B2).
    // Prefix at element m yields (P[m], hloc[m]) directly.
    //
    // C/D layout [m89]: col(n) = l16, row(m within frag) = quad*4 + r.
    // m order within wave: i (outer, 16 rows) -> quad (4 rows) -> r.
    // =======================================================================
    const int b   = m0 >> 13;             // m0 / L_
    const int chk = (m0 & (L_ - 1)) >> 7; // chunk index within batch

    float RunA[4], RunB[4];               // per-j running carry (quad-replicated)
#pragma unroll
    for (int j = 0; j < 4; ++j) {
        const int n = n0 + wcol * 64 + j * 16 + l16;
        const float bgv = bg[n];
        const float bcv = bc[n];
        float Ar = 1.f, Br = 0.f;
#pragma unroll
        for (int i = 0; i < 4; ++i) {
            // local inclusive scan over this lane's 4 consecutive rows
            float P[4], H[4];
            float pp = 1.f, ph = 0.f;
#pragma unroll
            for (int r = 0; r < 4; ++r) {
                float zg = accg[i][j][r] + bgv;
                float zc = accc[i][j][r] + bcv;
                float g = 1.f / (1.f + __expf(-zg));
                float c = tanhf(zc);
                float Pv = (r == 0) ? g : g * pp;
                float Hv = (r == 0) ? c : fmaf(g, ph, c);
                P[r] = Pv; H[r] = Hv; pp = Pv; ph = Hv;
            }
            // cross-quad inclusive scan of lane totals (P[3],H[3]); quads with
            // the same l16 hold the same channel at consecutive 4-row groups.
            float Ai = P[3], Bi = H[3];
            float A1 = __shfl(Ai, (lane - 16) & 63);
            float B1 = __shfl(Bi, (lane - 16) & 63);
            if (quad >= 1) { Bi = fmaf(Ai, B1, Bi); Ai *= A1; }
            float A2 = __shfl(Ai, (lane - 32) & 63);
            float B2 = __shfl(Bi, (lane - 32) & 63);
            if (quad >= 2) { Bi = fmaf(Ai, B2, Bi); Ai *= A2; }
            // exclusive prefix for this quad = inclusive of quad-1
            float Ae = __shfl(Ai, (lane - 16) & 63);
            float Be = __shfl(Bi, (lane - 16) & 63);
            if (quad == 0) { Ae = 1.f; Be = 0.f; }
            // pre-compose: C = E_quad ∘ Run
            float Ca = Ae * Ar;
            float Cb = fmaf(Ae, Br, Be);
            // element prefix = local ∘ C  -> write back (P, hloc) into acc
#pragma unroll
            for (int r = 0; r < 4; ++r) {
                float Pr = P[r];
                accg[i][j][r] = Pr * Ca;
                accc[i][j][r] = fmaf(Pr, Cb, H[r]);
            }
            // advance Run by the full 16-row group (quad 3 inclusive total)
            float Ag  = __shfl(Ai, l16 + 48);
            float Bg2 = __shfl(Bi, l16 + 48);
            Br = fmaf(Ag, Br, Bg2);
            Ar *= Ag;
        }
        RunA[j] = Ar; RunB[j] = Br;
    }

    // ---- cross-wave: wrow=0 (rows 0..63) publishes carry; wrow=1 applies ----
    if (wrow == 0 && quad == 0) {
#pragma unroll
        for (int j = 0; j < 4; ++j) {
            cw[wcol][j][l16][0] = RunA[j];
            cw[wcol][j][l16][1] = RunB[j];
        }
    }
    __syncthreads();
    if (wrow == 1) {
#pragma unroll
        for (int j = 0; j < 4; ++j) {
            float Aw = cw[wcol][j][l16][0];
            float Bw = cw[wcol][j][l16][1];
#pragma unroll
            for (int i = 0; i < 4; ++i) {
#pragma unroll
                for (int r = 0; r < 4; ++r) {
                    float Pe = accg[i][j][r];
                    accc[i][j][r] = fmaf(Pe, Bw, accc[i][j][r]);
                    accg[i][j][r] = Pe * Aw;
                }
            }
            if (quad == 0) {   // one lane set per channel writes chunk carry
                const int n = n0 + wcol * 64 + j * 16 + l16;
                size_t co = (((size_t)b * NCH + chk) << 10) + n;
                carryA[co] = RunA[j] * Aw;
                carryB[co] = fmaf(RunA[j], Bw, RunB[j]);
            }
        }
    }

    // ---- stores: P and hloc in [m][n] layout ----
#pragma unroll
    for (int j = 0; j < 4; ++j) {
        const int n = n0 + wcol * 64 + j * 16 + l16;
#pragma unroll
        for (int i = 0; i < 4; ++i) {
#pragma unroll
            for (int r = 0; r < 4; ++r) {
                int m = m0 + wrow * 64 + i * 16 + quad * 4 + r;
                size_t o = ((size_t)m << 10) + n;
                P_ws[o] = accg[i][j][r];
                h_ws[o] = accc[i][j][r];
            }
        }
    }
}

// ---------------------------------------------------------------------------
// Kernel 3: exclusive scan of chunk carries; carryB[k] <- h entering chunk k.
// ---------------------------------------------------------------------------
__global__ __launch_bounds__(256) void scan_carry_kernel(
    const float* __restrict__ carryA, float* __restrict__ carryB)
{
    const int idx = blockIdx.x * 256 + threadIdx.x;  // B_*D_ threads
    const int b = idx >> 10;
    const int d = idx & (D_ - 1);
    float acc = 0.f;
    for (int k = 0; k < NCH; ++k) {
        const size_t o = (((size_t)b * NCH + k) << 10) + d;
        const float a  = carryA[o];
        const float bb = carryB[o];
        carryB[o] = acc;
        acc = fmaf(a, acc, bb);
    }
}

// ---------------------------------------------------------------------------
// Kernel 4: elementwise apply: out = hloc + P * h_in  (pure streaming)
// ---------------------------------------------------------------------------
__global__ __launch_bounds__(256) void scan_apply_kernel(
    const float* __restrict__ P_ws, const float* __restrict__ h_ws,
    const float* __restrict__ carryB, float* __restrict__ out)
{
    const size_t o = ((size_t)blockIdx.x * 256 + threadIdx.x) * 4;
    const int m  = (int)(o >> 10);
    const int d  = (int)(o & (D_ - 1));
    const int b  = m >> 13;
    const int ch = (m & (L_ - 1)) >> 7;
    const float4 hin = *(const float4*)(carryB + ((((size_t)b * NCH + ch) << 10) + d));
    const float4 P = *(const float4*)(P_ws + o);
    const float4 H = *(const float4*)(h_ws + o);
    float4 r;
    r.x = fmaf(P.x, hin.x, H.x);
    r.y = fmaf(P.y, hin.y, H.y);
    r.z = fmaf(P.z, hin.z, H.z);
    r.w = fmaf(P.w, hin.w, H.w);
    *(float4*)(out + o) = r;
}

// ---------------------------------------------------------------------------
extern "C" void kernel_launch(void* const* d_in, const int* in_sizes, int n_in,
                              void* d_out, int out_size, void* d_ws, size_t ws_size,
                              hipStream_t stream)
{
    const float* x  = (const float*)d_in[0];
    const float* Wg = (const float*)d_in[1];
    const float* bg = (const float*)d_in[2];
    const float* Wc = (const float*)d_in[3];
    const float* bc = (const float*)d_in[4];
    float* out = (float*)d_out;

    // Workspace layout:
    //   P_ws   fp32 M*D      134.2 MB   (prefix gate product within chunk)
    //   h_ws   fp32 M*D      134.2 MB   (local scan result, h_in = 0)
    //   carryA fp32 B*NCH*D    1 MB
    //   carryB fp32 B*NCH*D    1 MB
    //   Wghi/Wglo/Wchi/Wclo  bf16 D*D  2 MB each   (total ~278 MB)
    float* ws = (float*)d_ws;
    float* P_ws   = ws;
    float* h_ws   = P_ws + (size_t)M_ * D_;
    float* carryA = h_ws + (size_t)M_ * D_;
    float* carryB = carryA + (size_t)B_ * NCH * D_;
    unsigned short* Wghi = (unsigned short*)(carryB + (size_t)B_ * NCH * D_);
    unsigned short* Wglo = Wghi + (size_t)D_ * D_;
    unsigned short* Wchi = Wglo + (size_t)D_ * D_;
    unsigned short* Wclo = Wchi + (size_t)D_ * D_;

    wprep_kernel<<<(2 * D_ * D_ / 4) / 256, 256, 0, stream>>>(
        Wg, Wc, Wghi, Wglo, Wchi, Wclo);

    gemm_scan_kernel<<<dim3(M_ / BM, D_ / BN), 256, 0, stream>>>(
        x, Wghi, Wglo, Wchi, Wclo, bg, bc, P_ws, h_ws, carryA, carryB);

    scan_carry_kernel<<<(B_ * D_) / 256, 256, 0, stream>>>(carryA, carryB);

    scan_apply_kernel<<<(M_ * (D_ / 4)) / 256, 256, 0, stream>>>(
        P_ws, h_ws, carryB, out);
}

// Round 2
// 696.865 us; speedup vs baseline: 1.0001x; 1.0001x over previous
//
#include <hip/hip_runtime.h>
#include <math.h>

// Problem constants
#define B_ 4
#define L_ 8192
#define D_ 1024
#define M_ (B_ * L_)   // 32768 rows
#define K_ D_          // 1024 reduction dim

// GEMM tiling: 128x128 out tile, BOTH gate+cand per block, BK=32, 4 waves
#define BM 128
#define BN 128
#define BK 32

// Scan chunking: one GEMM block row-tile == one chunk
#define NCH 64          // chunks per batch (L_/CHL)
#define CHL 128         // chunk length == BM

typedef short bf16x8 __attribute__((ext_vector_type(8)));
typedef float f32x4 __attribute__((ext_vector_type(4)));

__device__ __forceinline__ unsigned short f2bf(float f) {
    unsigned u = __float_as_uint(f);
    u += 0x7fff + ((u >> 16) & 1);   // RNE
    return (unsigned short)(u >> 16);
}
__device__ __forceinline__ float bf2f(unsigned short h) {
    return __uint_as_float(((unsigned)h) << 16);
}

__device__ __forceinline__ void async16(const void* g, void* l) {
    __builtin_amdgcn_global_load_lds(
        (const __attribute__((address_space(1))) unsigned int*)g,
        (__attribute__((address_space(3))) unsigned int*)l, 16, 0, 0);
}

// ---------------------------------------------------------------------------
// Weight prep: split Wg, Wc (fp32 [D,D]) into bf16 hi/lo planes.
// ---------------------------------------------------------------------------
__global__ __launch_bounds__(256) void wprep_kernel(
    const float* __restrict__ Wg, const float* __restrict__ Wc,
    unsigned short* __restrict__ Wghi, unsigned short* __restrict__ Wglo,
    unsigned short* __restrict__ Wchi, unsigned short* __restrict__ Wclo)
{
    int idx = (blockIdx.x * 256 + threadIdx.x) * 4;  // over 2*D*D elements
    const int n = D_ * D_;
    const float* src; unsigned short *dh, *dl; int o;
    if (idx < n) { src = Wg; dh = Wghi; dl = Wglo; o = idx; }
    else         { src = Wc; dh = Wchi; dl = Wclo; o = idx - n; }
    float4 v = *(const float4*)(src + o);
    ushort4 hi, lo;
    hi.x = f2bf(v.x); lo.x = f2bf(v.x - bf2f(hi.x));
    hi.y = f2bf(v.y); lo.y = f2bf(v.y - bf2f(hi.y));
    hi.z = f2bf(v.z); lo.z = f2bf(v.z - bf2f(hi.z));
    hi.w = f2bf(v.w); lo.w = f2bf(v.w - bf2f(hi.w));
    *(ushort4*)(dh + o) = hi;
    *(ushort4*)(dl + o) = lo;
}

// ---------------------------------------------------------------------------
// Fused dual GEMM (gate + cand in ONE block) + activation + in-register local
// scan over the 128-timestep chunk.
//
// This revision:
//  - XOR bank-conflict swizzle on all 6 LDS planes (T2):
//      k_elem ^= ((row&3)^((row>>2)&3))<<3
//    B planes: pre-swizzled GLOBAL source + linear DMA dest + swizzled read.
//    A planes: swizzled ds_write + swizzled read.
//  - B planes double-buffered with counted vmcnt(8) + raw s_barrier (T3/T4):
//    next tile's DMAs stay in flight across the barrier (never drain to 0).
//    X loads issued BEFORE the DMAs so their consumption waits vmcnt(8), not 0.
//  - LDS = 16 KB (A) + 64 KB (B dbuf) = 80 KB exactly -> 2 blocks/CU kept.
//    Epilogue cross-wave carry buffer overlays sAhi.
// ---------------------------------------------------------------------------
__global__ __launch_bounds__(256, 2) void gemm_scan_kernel(
    const float* __restrict__ X,
    const unsigned short* __restrict__ Wghi, const unsigned short* __restrict__ Wglo,
    const unsigned short* __restrict__ Wchi, const unsigned short* __restrict__ Wclo,
    const float* __restrict__ bg, const float* __restrict__ bc,
    float* __restrict__ P_ws, float* __restrict__ h_ws,
    float* __restrict__ carryA, float* __restrict__ carryB)
{
    __shared__ __align__(16) unsigned short sAhi[BM * BK];      // 8 KB
    __shared__ __align__(16) unsigned short sAlo[BM * BK];      // 8 KB
    __shared__ __align__(16) unsigned short sB[2][4][BN * BK];  // 64 KB dbuf x {ghi,glo,chi,clo}

    const int t = threadIdx.x;
    const int lane = t & 63;
    const int w = t >> 6;          // wave 0..3
    const int wrow = w >> 1;       // 0..1  (m half)
    const int wcol = w & 1;        // 0..1  (n half)
    const int quad = lane >> 4;    // 0..3
    const int l16  = lane & 15;

    const int m0 = blockIdx.x * BM;
    const int n0 = blockIdx.y * BN;

    // ---- swizzle constants (all per-thread compile-time-ish) ----
    // frag reads: row = ..16*i + l16 -> swz(row) = (l16&3)^((l16>>2)&3)
    const int rsw = (((l16 & 3) ^ ((l16 >> 2) & 3)) << 3);
    const int kq  = (quad << 3) ^ rsw;              // element offset within row
    // A ds_write: row = p*32 + (t>>3) -> swz = ((t>>3)&3)^((t>>5)&3)  (p-invariant)
    const int aws = ((((t >> 3) & 3) ^ ((t >> 5) & 3)) << 3);
    // B DMA source: row = p*64 + (t>>2), linear chunk = t&3 ->
    //   src chunk = (t&3) ^ ((t>>2)&3) ^ ((t>>4)&3)   (p-invariant)
    const int bSrcChunk = (((t & 3) ^ ((t >> 2) & 3) ^ ((t >> 4) & 3)) << 3);

    const unsigned short* const wp[4] = {Wghi, Wglo, Wchi, Wclo};

    f32x4 accg[4][4] = {};
    f32x4 accc[4][4] = {};

    // ---- prologue: stage B tile 0 into buffer 0 ----
#pragma unroll
    for (int p = 0; p < 2; ++p) {
        const int o   = t * 16 + p * 4096;          // byte offset in 8 KB plane
        const int row = (t >> 2) + p * 64;
        const size_t goff = (size_t)(n0 + row) * K_ + 0 + bSrcChunk;
#pragma unroll
        for (int pl = 0; pl < 4; ++pl)
            async16(wp[pl] + goff, (char*)sB[0][pl] + o);
    }

#pragma unroll 1
    for (int s = 0; s < 32; ++s) {
        const int k0  = s * BK;
        const int cur = s & 1;

        // barrier #1: previous step's LDS reads complete in all waves before
        // A overwrite and before DMA into sB[cur^1] (read 2 steps ago).
        asm volatile("" ::: "memory");
        __builtin_amdgcn_s_barrier();
        asm volatile("" ::: "memory");

        // ---- X loads FIRST (oldest vmem ops of this step) ----
        float4 xv[4];
#pragma unroll
        for (int p = 0; p < 4; ++p) {
            const int row = p * 32 + (t >> 3);
            const int k   = (t & 7) * 4;
            xv[p] = *(const float4*)(X + (size_t)(m0 + row) * K_ + k0 + k);
        }

        // ---- B staging for NEXT step: 8 async16, stay in flight ----
        if (s < 31) {
#pragma unroll
            for (int p = 0; p < 2; ++p) {
                const int o   = t * 16 + p * 4096;
                const int row = (t >> 2) + p * 64;
                const size_t goff = (size_t)(n0 + row) * K_ + (k0 + BK) + bSrcChunk;
#pragma unroll
                for (int pl = 0; pl < 4; ++pl)
                    async16(wp[pl] + goff, (char*)sB[cur ^ 1][pl] + o);
            }
        }

        // ---- A split -> swizzled ds_write (consumes xv: waits vmcnt(8)) ----
#pragma unroll
        for (int p = 0; p < 4; ++p) {
            const int row = p * 32 + (t >> 3);
            const int kk  = ((t & 7) * 4) ^ aws;
            float4 v = xv[p];
            ushort4 hi, lo;
            hi.x = f2bf(v.x); lo.x = f2bf(v.x - bf2f(hi.x));
            hi.y = f2bf(v.y); lo.y = f2bf(v.y - bf2f(hi.y));
            hi.z = f2bf(v.z); lo.z = f2bf(v.z - bf2f(hi.z));
            hi.w = f2bf(v.w); lo.w = f2bf(v.w - bf2f(hi.w));
            *(ushort4*)(sAhi + row * BK + kk) = hi;
            *(ushort4*)(sAlo + row * BK + kk) = lo;
        }

        // my A writes done; my B[cur] DMAs landed (8 newer allowed in flight)
        asm volatile("s_waitcnt lgkmcnt(0)" ::: "memory");
        asm volatile("s_waitcnt vmcnt(8)" ::: "memory");
        __builtin_amdgcn_sched_barrier(0);

        // barrier #2: everyone's A writes + B waits done
        __builtin_amdgcn_s_barrier();
        asm volatile("" ::: "memory");

        // ---- fragment loads (swizzled) + MFMA ----
        const unsigned short* __restrict__ sb0 = sB[cur][0];
        const unsigned short* __restrict__ sb1 = sB[cur][1];
        const unsigned short* __restrict__ sb2 = sB[cur][2];
        const unsigned short* __restrict__ sb3 = sB[cur][3];

        bf16x8 ahi[4], alo[4];
#pragma unroll
        for (int i = 0; i < 4; ++i) {
            const int off = (wrow * 64 + i * 16 + l16) * BK + kq;
            ahi[i] = *(const bf16x8*)(sAhi + off);
            alo[i] = *(const bf16x8*)(sAlo + off);
        }
#pragma unroll
        for (int j = 0; j < 4; ++j) {
            const int off = (wcol * 64 + j * 16 + l16) * BK + kq;
            bf16x8 bgh = *(const bf16x8*)(sb0 + off);
            bf16x8 bgl = *(const bf16x8*)(sb1 + off);
            bf16x8 bch = *(const bf16x8*)(sb2 + off);
            bf16x8 bcl = *(const bf16x8*)(sb3 + off);
#pragma unroll
            for (int i = 0; i < 4; ++i) {
                accg[i][j] = __builtin_amdgcn_mfma_f32_16x16x32_bf16(ahi[i], bgh, accg[i][j], 0, 0, 0);
                accg[i][j] = __builtin_amdgcn_mfma_f32_16x16x32_bf16(ahi[i], bgl, accg[i][j], 0, 0, 0);
                accg[i][j] = __builtin_amdgcn_mfma_f32_16x16x32_bf16(alo[i], bgh, accg[i][j], 0, 0, 0);
                accc[i][j] = __builtin_amdgcn_mfma_f32_16x16x32_bf16(ahi[i], bch, accc[i][j], 0, 0, 0);
                accc[i][j] = __builtin_amdgcn_mfma_f32_16x16x32_bf16(ahi[i], bcl, accc[i][j], 0, 0, 0);
                accc[i][j] = __builtin_amdgcn_mfma_f32_16x16x32_bf16(alo[i], bch, accc[i][j], 0, 0, 0);
            }
        }
        // no trailing barrier: next iteration's barrier #1 covers the hazard
    }

    // =======================================================================
    // Epilogue: bias + activation + in-register affine prefix scan over the
    // 128 timesteps of this chunk. Affine map per step: h -> g*h + c.
    // C/D layout [m89]: col(n) = l16, row(m within frag) = quad*4 + r.
    // =======================================================================
    const int b   = m0 >> 13;             // m0 / L_
    const int chk = (m0 & (L_ - 1)) >> 7; // chunk index within batch

    float RunA[4], RunB[4];               // per-j running carry (quad-replicated)
#pragma unroll
    for (int j = 0; j < 4; ++j) {
        const int n = n0 + wcol * 64 + j * 16 + l16;
        const float bgv = bg[n];
        const float bcv = bc[n];
        float Ar = 1.f, Br = 0.f;
#pragma unroll
        for (int i = 0; i < 4; ++i) {
            // local inclusive scan over this lane's 4 consecutive rows
            float P[4], H[4];
            float pp = 1.f, ph = 0.f;
#pragma unroll
            for (int r = 0; r < 4; ++r) {
                float zg = accg[i][j][r] + bgv;
                float zc = accc[i][j][r] + bcv;
                float g = 1.f / (1.f + __expf(-zg));
                float c = tanhf(zc);
                float Pv = (r == 0) ? g : g * pp;
                float Hv = (r == 0) ? c : fmaf(g, ph, c);
                P[r] = Pv; H[r] = Hv; pp = Pv; ph = Hv;
            }
            // cross-quad inclusive scan of lane totals (P[3],H[3])
            float Ai = P[3], Bi = H[3];
            float A1 = __shfl(Ai, (lane - 16) & 63);
            float B1 = __shfl(Bi, (lane - 16) & 63);
            if (quad >= 1) { Bi = fmaf(Ai, B1, Bi); Ai *= A1; }
            float A2 = __shfl(Ai, (lane - 32) & 63);
            float B2 = __shfl(Bi, (lane - 32) & 63);
            if (quad >= 2) { Bi = fmaf(Ai, B2, Bi); Ai *= A2; }
            // exclusive prefix for this quad = inclusive of quad-1
            float Ae = __shfl(Ai, (lane - 16) & 63);
            float Be = __shfl(Bi, (lane - 16) & 63);
            if (quad == 0) { Ae = 1.f; Be = 0.f; }
            // pre-compose: C = E_quad ∘ Run
            float Ca = Ae * Ar;
            float Cb = fmaf(Ae, Br, Be);
            // element prefix = local ∘ C  -> write back (P, hloc) into acc
#pragma unroll
            for (int r = 0; r < 4; ++r) {
                float Pr = P[r];
                accg[i][j][r] = Pr * Ca;
                accc[i][j][r] = fmaf(Pr, Cb, H[r]);
            }
            // advance Run by the full 16-row group (quad 3 inclusive total)
            float Ag  = __shfl(Ai, l16 + 48);
            float Bg2 = __shfl(Bi, l16 + 48);
            Br = fmaf(Ag, Br, Bg2);
            Ar *= Ag;
        }
        RunA[j] = Ar; RunB[j] = Br;
    }

    // ---- cross-wave carry exchange: cw overlays sAhi (16 KB >> 1 KB) ----
    __syncthreads();   // all waves done with sAhi frag reads before reuse
    float* cwf = (float*)sAhi;   // layout [2][4][16][2]

    if (wrow == 0 && quad == 0) {
#pragma unroll
        for (int j = 0; j < 4; ++j) {
            cwf[(((wcol * 4 + j) * 16 + l16) << 1) + 0] = RunA[j];
            cwf[(((wcol * 4 + j) * 16 + l16) << 1) + 1] = RunB[j];
        }
    }
    __syncthreads();
    if (wrow == 1) {
#pragma unroll
        for (int j = 0; j < 4; ++j) {
            float Aw = cwf[(((wcol * 4 + j) * 16 + l16) << 1) + 0];
            float Bw = cwf[(((wcol * 4 + j) * 16 + l16) << 1) + 1];
#pragma unroll
            for (int i = 0; i < 4; ++i) {
#pragma unroll
                for (int r = 0; r < 4; ++r) {
                    float Pe = accg[i][j][r];
                    accc[i][j][r] = fmaf(Pe, Bw, accc[i][j][r]);
                    accg[i][j][r] = Pe * Aw;
                }
            }
            if (quad == 0) {   // one lane set per channel writes chunk carry
                const int n = n0 + wcol * 64 + j * 16 + l16;
                size_t co = (((size_t)b * NCH + chk) << 10) + n;
                carryA[co] = RunA[j] * Aw;
                carryB[co] = fmaf(RunA[j], Bw, RunB[j]);
            }
        }
    }

    // ---- stores: P and hloc in [m][n] layout ----
#pragma unroll
    for (int j = 0; j < 4; ++j) {
        const int n = n0 + wcol * 64 + j * 16 + l16;
#pragma unroll
        for (int i = 0; i < 4; ++i) {
#pragma unroll
            for (int r = 0; r < 4; ++r) {
                int m = m0 + wrow * 64 + i * 16 + quad * 4 + r;
                size_t o = ((size_t)m << 10) + n;
                P_ws[o] = accg[i][j][r];
                h_ws[o] = accc[i][j][r];
            }
        }
    }
}

// ---------------------------------------------------------------------------
// Kernel 3: exclusive scan of chunk carries; carryB[k] <- h entering chunk k.
// ---------------------------------------------------------------------------
__global__ __launch_bounds__(256) void scan_carry_kernel(
    const float* __restrict__ carryA, float* __restrict__ carryB)
{
    const int idx = blockIdx.x * 256 + threadIdx.x;  // B_*D_ threads
    const int b = idx >> 10;
    const int d = idx & (D_ - 1);
    float acc = 0.f;
    for (int k = 0; k < NCH; ++k) {
        const size_t o = (((size_t)b * NCH + k) << 10) + d;
        const float a  = carryA[o];
        const float bb = carryB[o];
        carryB[o] = acc;
        acc = fmaf(a, acc, bb);
    }
}

// ---------------------------------------------------------------------------
// Kernel 4: elementwise apply: out = hloc + P * h_in  (pure streaming)
// ---------------------------------------------------------------------------
__global__ __launch_bounds__(256) void scan_apply_kernel(
    const float* __restrict__ P_ws, const float* __restrict__ h_ws,
    const float* __restrict__ carryB, float* __restrict__ out)
{
    const size_t o = ((size_t)blockIdx.x * 256 + threadIdx.x) * 4;
    const int m  = (int)(o >> 10);
    const int d  = (int)(o & (D_ - 1));
    const int b  = m >> 13;
    const int ch = (m & (L_ - 1)) >> 7;
    const float4 hin = *(const float4*)(carryB + ((((size_t)b * NCH + ch) << 10) + d));
    const float4 P = *(const float4*)(P_ws + o);
    const float4 H = *(const float4*)(h_ws + o);
    float4 r;
    r.x = fmaf(P.x, hin.x, H.x);
    r.y = fmaf(P.y, hin.y, H.y);
    r.z = fmaf(P.z, hin.z, H.z);
    r.w = fmaf(P.w, hin.w, H.w);
    *(float4*)(out + o) = r;
}

// ---------------------------------------------------------------------------
extern "C" void kernel_launch(void* const* d_in, const int* in_sizes, int n_in,
                              void* d_out, int out_size, void* d_ws, size_t ws_size,
                              hipStream_t stream)
{
    const float* x  = (const float*)d_in[0];
    const float* Wg = (const float*)d_in[1];
    const float* bg = (const float*)d_in[2];
    const float* Wc = (const float*)d_in[3];
    const float* bc = (const float*)d_in[4];
    float* out = (float*)d_out;

    // Workspace layout:
    //   P_ws   fp32 M*D      134.2 MB   (prefix gate product within chunk)
    //   h_ws   fp32 M*D      134.2 MB   (local scan result, h_in = 0)
    //   carryA fp32 B*NCH*D    1 MB
    //   carryB fp32 B*NCH*D    1 MB
    //   Wghi/Wglo/Wchi/Wclo  bf16 D*D  2 MB each   (total ~278 MB)
    float* ws = (float*)d_ws;
    float* P_ws   = ws;
    float* h_ws   = P_ws + (size_t)M_ * D_;
    float* carryA = h_ws + (size_t)M_ * D_;
    float* carryB = carryA + (size_t)B_ * NCH * D_;
    unsigned short* Wghi = (unsigned short*)(carryB + (size_t)B_ * NCH * D_);
    unsigned short* Wglo = Wghi + (size_t)D_ * D_;
    unsigned short* Wchi = Wglo + (size_t)D_ * D_;
    unsigned short* Wclo = Wchi + (size_t)D_ * D_;

    wprep_kernel<<<(2 * D_ * D_ / 4) / 256, 256, 0, stream>>>(
        Wg, Wc, Wghi, Wglo, Wchi, Wclo);

    gemm_scan_kernel<<<dim3(M_ / BM, D_ / BN), 256, 0, stream>>>(
        x, Wghi, Wglo, Wchi, Wclo, bg, bc, P_ws, h_ws, carryA, carryB);

    scan_carry_kernel<<<(B_ * D_) / 256, 256, 0, stream>>>(carryA, carryB);

    scan_apply_kernel<<<(M_ * (D_ / 4)) / 256, 256, 0, stream>>>(
        P_ws, h_ws, carryB, out);
}